// Round 1
// baseline (233.529 us; speedup 1.0000x reference)
//
#include <hip/hip_runtime.h>

// Problem dims (fixed by reference setup_inputs):
//   x: (64, 65536, 10) f32, labels 0..9
//   B=64, C=10, D=65536, K=8, NJ=D/K=8192
//   window (b,c,j) = in[(b*C+c)*D + j*8 .. +8)
//   out[c*NJ*B + j*B + b] = mode(window), ties -> smallest value
#define BB 64
#define CC 10
#define DD 65536
#define KK 8
#define NJ 8192          // DD / KK
#define JT 64            // j-tile per block
#define NBLK_J (NJ / JT) // 128

__global__ __launch_bounds__(256) void mode_pool_kernel(const float* __restrict__ in,
                                                        float* __restrict__ out) {
    // block: c = blockIdx.x >> 7, j0 = (blockIdx.x & 127) * JT
    const int c  = blockIdx.x >> 7;
    const int j0 = (blockIdx.x & (NBLK_J - 1)) * JT;
    const int tid  = threadIdx.x;
    const int lane = tid & 63;

    // lds[j_local][b], padded row stride 65 -> (lane+b)%32 bank pattern (2-way, free)
    __shared__ float lds[JT * 65];

    // Phase 1: compute modes. Flat loop i = tid + k*256 over 4096 windows.
    // j_local = i & 63 == lane (coalesced reads), b = i >> 6.
    #pragma unroll
    for (int k = 0; k < 16; ++k) {
        const int i = tid + k * 256;
        const int b = i >> 6;          // 0..63
        const int jl = lane;           // i & 63
        const size_t base = ((size_t)(b * CC + c)) * DD + (size_t)(j0 + jl) * KK;

        const float4 lo = *(const float4*)(in + base);
        const float4 hi = *(const float4*)(in + base + 4);
        float v[8] = {lo.x, lo.y, lo.z, lo.w, hi.x, hi.y, hi.z, hi.w};

        int bc = 0;
        float bv = 1e30f;
        #pragma unroll
        for (int a = 0; a < 8; ++a) {
            int cnt = 0;
            #pragma unroll
            for (int q = 0; q < 8; ++q) cnt += (v[q] == v[a]) ? 1 : 0;
            const bool better = (cnt > bc) || (cnt == bc && v[a] < bv);
            bc = better ? cnt : bc;
            bv = better ? v[a] : bv;
        }
        lds[jl * 65 + b] = bv;
    }

    __syncthreads();

    // Phase 2: contiguous float4 stores of the 4096-float tile.
    // out chunk base = c*NJ*B + j0*B, layout within chunk: pos = j_local*64 + b.
    float4* outv = (float4*)(out + (size_t)c * NJ * BB + (size_t)j0 * BB);
    #pragma unroll
    for (int k = 0; k < 4; ++k) {
        const int v4 = tid + k * 256;        // 0..1023
        const int row = v4 >> 4;             // j_local
        const int col = (v4 & 15) * 4;       // b base
        const float* p = &lds[row * 65 + col];
        float4 o;
        o.x = p[0]; o.y = p[1]; o.z = p[2]; o.w = p[3];
        outv[v4] = o;
    }
}

extern "C" void kernel_launch(void* const* d_in, const int* in_sizes, int n_in,
                              void* d_out, int out_size, void* d_ws, size_t ws_size,
                              hipStream_t stream) {
    const float* in = (const float*)d_in[0];
    float* out = (float*)d_out;
    dim3 grid(CC * NBLK_J);  // 1280 blocks
    dim3 block(256);
    mode_pool_kernel<<<grid, block, 0, stream>>>(in, out);
}